// Round 9
// baseline (441.555 us; speedup 1.0000x reference)
//
#include <hip/hip_runtime.h>
#include <stdint.h>

typedef __attribute__((ext_vector_type(8))) short short8;
typedef __attribute__((ext_vector_type(4))) float f32x4;

#define MFMA16 __builtin_amdgcn_mfma_f32_16x16x32_bf16
#define PFENCE() asm volatile("" ::: "memory")

static constexpr int kOutD   = 320;
static constexpr int THREADS = 1024;              // 16 waves, 1 block/CU
static constexpr int NBLOCKS = 256;
static constexpr int NTILES  = 262144 / 64;       // 4096 tiles of 64 nodes
static constexpr int ITERS   = NTILES / NBLOCKS;  // 16

// ---- LDS byte offsets (R1 footprint, 145.25 KB) ----
static constexpr int W1S = 0;        // [192][256B]  W1_s^T (row h, col k), swizzled
static constexpr int W2S = 49152;    // [128][256B]  W2_s^T (row o, col h), swizzled
static constexpr int W1V = 81920;    // [64][128B]   W1_v^T (row j, col i), swizzled
static constexpr int W2V = 90112;    // [64][128B]   W2_v^T
static constexpr int B1O = 98304;    // 192 f32
static constexpr int B2O = 99072;    // 128 f32
static constexpr int XS  = 99584;    // [64][256B]   x_s bf16; overlaid by scal (SC)
static constexpr int XV  = 115968;   // [192][128B]  x_v bf16 rows rr=3n+c; overlaid by VG
static constexpr int GT  = 140544;   // [64][128B]   gates bf16
static constexpr int SMEM_BYTES = 148736;

__device__ __forceinline__ uint16_t f2bf(float f) {
  uint32_t u = __builtin_bit_cast(uint32_t, f);
  u += 0x7FFFu + ((u >> 16) & 1u);          // RNE
  return (uint16_t)(u >> 16);
}
__device__ __forceinline__ float bf2f(uint16_t u) {
  return __builtin_bit_cast(float, ((uint32_t)u) << 16);
}

extern "C" __global__ __launch_bounds__(THREADS, 4)
void fused_gate_mlp(const float* __restrict__ x_s, const float* __restrict__ x_v,
                    const float* __restrict__ W1_s, const float* __restrict__ b1_s,
                    const float* __restrict__ W1_v, const float* __restrict__ W2_s,
                    const float* __restrict__ b2_s, const float* __restrict__ W2_v,
                    float* __restrict__ out)
{
  extern __shared__ char smem[];
  const int tid = threadIdx.x;

  // ---------- stage weights once per block ----------
  for (int idx = tid; idx < 128 * 192; idx += THREADS) {       // W1_s [k][h] -> [h][k]
    int k = idx / 192, h = idx - k * 192;
    *(uint16_t*)(smem + W1S + h * 256 + ((2 * k) ^ ((h & 7) << 4))) = f2bf(W1_s[idx]);
  }
  for (int idx = tid; idx < 128 * 128; idx += THREADS) {       // W2_s [h][o] -> [o][h]
    int k = idx >> 7, o = idx & 127;
    *(uint16_t*)(smem + W2S + o * 256 + ((2 * k) ^ ((o & 7) << 4))) = f2bf(W2_s[idx]);
  }
  for (int idx = tid; idx < 64 * 64; idx += THREADS) {         // W1_v/W2_v [i][j] -> [j][i]
    int i = idx >> 6, j = idx & 63;
    int off = j * 128 + ((2 * i) ^ ((j & 7) << 4));
    *(uint16_t*)(smem + W1V + off) = f2bf(W1_v[idx]);
    *(uint16_t*)(smem + W2V + off) = f2bf(W2_v[idx]);
  }
  if (tid < 192) ((float*)(smem + B1O))[tid] = b1_s[tid];
  if (tid < 128) ((float*)(smem + B2O))[tid] = b2_s[tid];

  const int w  = tid >> 6;           // wave 0..15
  const int l  = tid & 63;
  const int lw = l & 15;
  const int lg = l >> 4;
  const int sx = (lw & 7) << 4;
  const int mt = w >> 2;             // node group 0..3 (16 nodes each)
  const int nh = w & 3;              // column quarter 0..3
  const int m0 = mt * 16;
  const int rv0 = mt * 48;           // vector-row base (rr = 3n+c)
  const float* b1 = (const float*)(smem + B1O);
  const float* b2 = (const float*)(smem + B2O);

  const float inv_s = 0.08838834764831845f;  // 1/sqrt(128)
  const float inv_v = 0.125f;                // 1/sqrt(64)

  int tile = blockIdx.x;

  // ---------- prime x_s prefetch of tile 0 (2 float4/thread) ----------
  float4 pfs[2];
  {
    const float4* ps = (const float4*)(x_s + (size_t)tile * 64 * 128);
#pragma unroll
    for (int p = 0; p < 2; ++p) pfs[p] = ps[tid + p * THREADS];
  }

#pragma unroll 1
  for (int t = 0; t < ITERS; ++t) {
    const int node0 = tile * 64;
    float* orow = out + (size_t)node0 * kOutD;

    __syncthreads();   // B0: prev tile's SC/VG/GT reads done; XS/XV free

    PFENCE();
    // ---- issue x_v loads for THIS tile (3 float4/thread) ----
    float4 pfv[3];
    {
      const float4* pv = (const float4*)(x_v + (size_t)tile * 64 * 192);
#pragma unroll
      for (int p = 0; p < 3; ++p) pfv[p] = pv[tid + p * THREADS];
    }
    PFENCE();

    // ---- stage x_s (pfs dies) ----
#pragma unroll
    for (int p = 0; p < 2; ++p) {
      int idx4 = tid + p * THREADS;
      int n = idx4 >> 5;
      int kb2 = (idx4 & 31) * 8;
      uint2 v;
      v.x = (uint32_t)f2bf(pfs[p].x) | ((uint32_t)f2bf(pfs[p].y) << 16);
      v.y = (uint32_t)f2bf(pfs[p].z) | ((uint32_t)f2bf(pfs[p].w) << 16);
      *(uint2*)(smem + XS + n * 256 + (kb2 ^ ((n & 7) << 4))) = v;
    }
    // ---- stage x_v -> rows rr=3n+c (pfv dies) ----
#pragma unroll
    for (int p = 0; p < 3; ++p) {
      unsigned idx4 = (unsigned)tid + p * THREADS;
      unsigned n = idx4 / 48, rem = idx4 - n * 48;
      float v[4] = {pfv[p].x, pfv[p].y, pfv[p].z, pfv[p].w};
#pragma unroll
      for (int e = 0; e < 4; ++e) {
        unsigned fe = rem * 4 + e, i = fe / 3, c = fe - i * 3, rr = n * 3 + c;
        *(uint16_t*)(smem + XV + rr * 128 + ((2 * i) ^ ((rr & 7) << 4))) = f2bf(v[e]);
      }
    }

    __syncthreads();   // B1: staging visible (also bias on iter 0)

    // ---- A-fragments ----
    short8 axs[4];
#pragma unroll
    for (int kt = 0; kt < 4; ++kt)
      axs[kt] = *(const short8*)(smem + XS + (m0 + lw) * 256 + ((kt * 64 + lg * 16) ^ sx));
    short8 axv[3][2];
#pragma unroll
    for (int m2 = 0; m2 < 3; ++m2)
#pragma unroll
      for (int kt = 0; kt < 2; ++kt)
        axv[m2][kt] = *(const short8*)(smem + XV + (rv0 + m2 * 16 + lw) * 128 + ((kt * 64 + lg * 16) ^ sx));

    // ---- s1 = x_s @ W1_s (3 frags: column quarter) ----
    f32x4 accs[3];
#pragma unroll
    for (int i = 0; i < 3; ++i) accs[i] = (f32x4){0.f, 0.f, 0.f, 0.f};
#pragma unroll
    for (int kt = 0; kt < 4; ++kt) {
      const int kb = (kt * 64 + lg * 16) ^ sx;
#pragma unroll
      for (int hf = 0; hf < 3; ++hf) {
        const int h = nh * 48 + hf * 16 + lw;
        short8 b = *(const short8*)(smem + W1S + h * 256 + kb);
        accs[hf] = MFMA16(axs[kt], b, accs[hf], 0, 0, 0);
      }
    }

    // ---- v1 = x_v . W1_v (j quarter: 1 frag x 3 row-blocks) ----
    f32x4 accv[3];
#pragma unroll
    for (int i = 0; i < 3; ++i) accv[i] = (f32x4){0.f, 0.f, 0.f, 0.f};
#pragma unroll
    for (int kt = 0; kt < 2; ++kt) {
      const int kb = (kt * 64 + lg * 16) ^ sx;
      short8 b = *(const short8*)(smem + W1V + (nh * 16 + lw) * 128 + kb);
#pragma unroll
      for (int m2 = 0; m2 < 3; ++m2)
        accv[m2] = MFMA16(axv[m2][kt], b, accv[m2], 0, 0, 0);
    }

    __syncthreads();   // B2: all XS/XV fragment reads done

    // ---- act: scal -> SC (over XS), gates -> GT ----
#pragma unroll
    for (int hf = 0; hf < 3; ++hf) {
      const int h = nh * 48 + hf * 16 + lw;
      const float bb = b1[h];
#pragma unroll
      for (int r = 0; r < 4; ++r) {
        const int m = m0 + lg * 4 + r;
        float v = accs[hf][r] * inv_s + bb;
        float sg = 1.0f / (1.0f + __expf(-v));
        if (nh * 48 + hf * 16 < 128)   // frag-uniform split
          *(uint16_t*)(smem + XS + m * 256 + ((2 * h) ^ ((m & 7) << 4))) = f2bf(v * sg);
        else
          *(uint16_t*)(smem + GT + m * 128 + 2 * (h - 128)) = f2bf(sg);
      }
    }

    __syncthreads();   // B3: SC + GT visible

    // ---- scal A-fragments (before VG clobbers XV region; SC!=XV anyway) ----
    short8 as2[4];
#pragma unroll
    for (int kt = 0; kt < 4; ++kt)
      as2[kt] = *(const short8*)(smem + XS + (m0 + lw) * 256 + ((kt * 64 + lg * 16) ^ sx));

    // ---- v_g = v1 * gate -> VG (over XV) ----
#pragma unroll
    for (int m2 = 0; m2 < 3; ++m2)
#pragma unroll
      for (int r = 0; r < 4; ++r) {
        const unsigned rr = rv0 + m2 * 16 + lg * 4 + r;
        const unsigned n = rr / 3;
        const int j = nh * 16 + lw;
        const float g = bf2f(*(const uint16_t*)(smem + GT + n * 128 + 2 * j));
        float vgv = accv[m2][r] * inv_v * g;
        *(uint16_t*)(smem + XV + rr * 128 + ((2 * j) ^ ((rr & 7) << 4))) = f2bf(vgv);
      }

    __syncthreads();   // B4: VG visible

    // ---- out_s = scal @ W2_s (2 frags), store ----
    {
      f32x4 acco[2];
#pragma unroll
      for (int i = 0; i < 2; ++i) acco[i] = (f32x4){0.f, 0.f, 0.f, 0.f};
#pragma unroll
      for (int kt = 0; kt < 4; ++kt) {
        const int kb = (kt * 64 + lg * 16) ^ sx;
#pragma unroll
        for (int ot = 0; ot < 2; ++ot) {
          const int o = nh * 32 + ot * 16 + lw;
          short8 b = *(const short8*)(smem + W2S + o * 256 + kb);
          acco[ot] = MFMA16(as2[kt], b, acco[ot], 0, 0, 0);
        }
      }
#pragma unroll
      for (int ot = 0; ot < 2; ++ot) {
        const int o = nh * 32 + ot * 16 + lw;
        const float bb = b2[o];
#pragma unroll
        for (int r = 0; r < 4; ++r)
          orow[(size_t)(m0 + lg * 4 + r) * kOutD + o] = acco[ot][r] * inv_s + bb;
      }
    }

    PFENCE();
    // ---- prefetch x_s of NEXT tile (covered by out_v phase) ----
    const int ntile = (tile + NBLOCKS) & (NTILES - 1);
    {
      const float4* ps = (const float4*)(x_s + (size_t)ntile * 64 * 128);
#pragma unroll
      for (int p = 0; p < 2; ++p) pfs[p] = ps[tid + p * THREADS];
    }
    PFENCE();

    // ---- out_v = v_g . W2_v (1 frag x 3 row-blocks), store ----
    {
      short8 avg_[3][2];
#pragma unroll
      for (int m2 = 0; m2 < 3; ++m2)
#pragma unroll
        for (int kt = 0; kt < 2; ++kt)
          avg_[m2][kt] = *(const short8*)(smem + XV + (rv0 + m2 * 16 + lw) * 128 + ((kt * 64 + lg * 16) ^ sx));
      f32x4 accw[3];
#pragma unroll
      for (int i = 0; i < 3; ++i) accw[i] = (f32x4){0.f, 0.f, 0.f, 0.f};
      const int j2 = nh * 16 + lw;
#pragma unroll
      for (int kt = 0; kt < 2; ++kt) {
        const int kb = (kt * 64 + lg * 16) ^ sx;
        short8 b = *(const short8*)(smem + W2V + j2 * 128 + kb);
#pragma unroll
        for (int m2 = 0; m2 < 3; ++m2)
          accw[m2] = MFMA16(avg_[m2][kt], b, accw[m2], 0, 0, 0);
      }
#pragma unroll
      for (int m2 = 0; m2 < 3; ++m2)
#pragma unroll
        for (int r = 0; r < 4; ++r) {
          const unsigned rr = rv0 + m2 * 16 + lg * 4 + r;
          const unsigned n = rr / 3, c = rr - 3 * n;
          orow[(size_t)n * kOutD + 128 + j2 * 3 + c] = accw[m2][r] * inv_v;
        }
    }

    tile = ntile;
  }
}

extern "C" void kernel_launch(void* const* d_in, const int* in_sizes, int n_in,
                              void* d_out, int out_size, void* d_ws, size_t ws_size,
                              hipStream_t stream) {
  const float* x_s  = (const float*)d_in[0];
  const float* x_v  = (const float*)d_in[1];
  const float* W1_s = (const float*)d_in[2];
  const float* b1_s = (const float*)d_in[3];
  const float* W1_v = (const float*)d_in[4];
  const float* W2_s = (const float*)d_in[5];
  const float* b2_s = (const float*)d_in[6];
  const float* W2_v = (const float*)d_in[7];
  float* o = (float*)d_out;
  hipLaunchKernelGGL(fused_gate_mlp, dim3(NBLOCKS), dim3(THREADS), SMEM_BYTES, stream,
                     x_s, x_v, W1_s, b1_s, W1_v, W2_s, b2_s, W2_v, o);
}